// Round 14
// baseline (52.092 us; speedup 1.0000x reference)
//
#include <hip/hip_runtime.h>
#include <math.h>

namespace fc {

typedef float vf2 __attribute__((ext_vector_type(2)));
typedef float vf4 __attribute__((ext_vector_type(4)));

__device__ __forceinline__ vf2 sp(float c) { return vf2{c, c}; }

constexpr float ACT_SCALE = 10.0f;
constexpr float U_HOVER   = 0.515025f;          // -MASS*-9.81/10/1/4
constexpr float INV_MASS  = 1.0f / 2.1f;
constexpr float KM        = 0.025f;
constexpr float TAUC      = 0.175f * 0.70710678f; // MOTOR_DIST / sqrt(2)
constexpr float JXY       = 0.0023f;
constexpr float JZ        = 0.004f;
constexpr float INV_JXY   = 1.0f / 0.0023f;
constexpr float INV_JZ    = 1.0f / 0.004f;
constexpr float G3        = -9.81f;
constexpr float INV_L     = 2.0f;
constexpr float DT        = 0.05f;
constexpr float DT2       = 0.05f * 0.5f;
constexpr float DT6       = 0.05f / 6.0f;

// Packed (2 rows/lane) dynamics. FzM = Fz/MASS precomputed (stage-invariant).
__device__ __forceinline__ void dyn2(const vf2* xt, vf2 FzM,
                                     vf2 taux, vf2 tauy, vf2 tauz, vf2* dx) {
  vf2 mx = xt[3], my = xt[4], mz = xt[5], th = xt[6];
  vf2 vx = xt[7], vy = xt[8], vz = xt[9];
  vf2 wx = xt[10], wy = xt[11], wz = xt[12];

  vf2 n2 = mx * mx + my * my + mz * mz;
  vf2 inv;
  inv.x = __builtin_amdgcn_rcpf(1.0f + n2.x);
  inv.y = __builtin_amdgcn_rcpf(1.0f + n2.y);
  vf2 s  = (sp(1.0f) - n2) * inv;
  vf2 qx = sp(2.0f) * mx * inv;
  vf2 qy = sp(2.0f) * my * inv;
  vf2 qz = sp(2.0f) * mz * inv;

  // gravity rotation quatrot(-q, (0,0,g)) hand-specialized (exact: dropped
  // terms are *0.0); g applied directly (MASS*g/MASS folded).
  vf2 gtx = qy * sp(-G3);
  vf2 gty = qx * sp(G3);
  vf2 gtz = s * sp(G3);
  vf2 gx = sp(-2.0f) * (qy * gtz - qz * gty);
  vf2 gy = sp(-2.0f) * (qz * gtx - qx * gtz);
  vf2 gz = sp(G3) + sp(-2.0f) * (qx * gty - qy * gtx);

  // pdot = quatrot(q, v)
  vf2 tx = qy * vz - qz * vy + s * vx;
  vf2 ty = qz * vx - qx * vz + s * vy;
  vf2 tz = qx * vy - qy * vx + s * vz;
  dx[0] = vx + sp(2.0f) * (qy * tz - qz * ty);
  dx[1] = vy + sp(2.0f) * (qz * tx - qx * tz);
  dx[2] = vz + sp(2.0f) * (qx * ty - qy * tx);

  // mdot
  vf2 mw  = mx * wx + my * wy + mz * wz;
  vf2 on2 = sp(1.0f) - n2;
  dx[3] = sp(0.25f) * (on2 * wx + sp(2.0f) * (my * wz - mz * wy) + sp(2.0f) * mx * mw);
  dx[4] = sp(0.25f) * (on2 * wy + sp(2.0f) * (mz * wx - mx * wz) + sp(2.0f) * my * mw);
  dx[5] = sp(0.25f) * (on2 * wz + sp(2.0f) * (mx * wy - my * wx) + sp(2.0f) * mz * mw);

  dx[6] = xt[13];

  // vdot = (0,0,Fz/M) + g' - w x v
  vf2 vdx = gx - (wy * vz - wz * vy);
  vf2 vdy = gy - (wz * vx - wx * vz);
  vf2 vdz = FzM + gz - (wx * vy - wy * vx);
  dx[7] = vdx; dx[8] = vdy; dx[9] = vdz;

  // wdot
  vf2 Jwx = sp(JXY) * wx, Jwy = sp(JXY) * wy, Jwz = sp(JZ) * wz;
  dx[10] = (taux - (wy * Jwz - wz * Jwy)) * sp(INV_JXY);
  dx[11] = (tauy - (wz * Jwx - wx * Jwz)) * sp(INV_JXY);
  dx[12] = (tauz - (wx * Jwy - wy * Jwx)) * sp(INV_JZ);

  // x_ddot = quatrot(q, vdot).x only
  vf2 t2y = qz * vdx - qx * vdz + s * vdy;
  vf2 t2z = qx * vdy - qy * vdx + s * vdz;
  vf2 rx  = vdx + sp(2.0f) * (qy * t2z - qz * t2y);
  vf2 st, ct;
  st.x = __sinf(th.x); st.y = __sinf(th.y);
  ct.x = __cosf(th.x); ct.y = __cosf(th.y);
  dx[13] = (sp(G3) * st + rx * ct) * sp(INV_L);
}

__device__ __forceinline__ void rk4_core(const vf2* x0, vf2 FzM,
                                         vf2 taux, vf2 tauy, vf2 tauz, vf2* o) {
  vf2 xt[14], kk[14], acc[14];
  dyn2(x0, FzM, taux, tauy, tauz, kk);
  #pragma unroll
  for (int j = 0; j < 14; ++j) { acc[j] = kk[j]; xt[j] = x0[j] + sp(DT2) * kk[j]; }
  dyn2(xt, FzM, taux, tauy, tauz, kk);
  #pragma unroll
  for (int j = 0; j < 14; ++j) { acc[j] += sp(2.0f) * kk[j]; xt[j] = x0[j] + sp(DT2) * kk[j]; }
  dyn2(xt, FzM, taux, tauy, tauz, kk);
  #pragma unroll
  for (int j = 0; j < 14; ++j) { acc[j] += sp(2.0f) * kk[j]; xt[j] = x0[j] + sp(DT) * kk[j]; }
  dyn2(xt, FzM, taux, tauy, tauz, kk);
  #pragma unroll
  for (int j = 0; j < 14; ++j) o[j] = x0[j] + sp(DT6) * (acc[j] + kk[j]);
}

__device__ __forceinline__ void utau(vf4 uA, vf4 uB, vf2& FzM,
                                     vf2& taux, vf2& tauy, vf2& tauz) {
  vf2 su0 = sp(ACT_SCALE) * (vf2{uA.x, uB.x} + sp(U_HOVER));
  vf2 su1 = sp(ACT_SCALE) * (vf2{uA.y, uB.y} + sp(U_HOVER));
  vf2 su2 = sp(ACT_SCALE) * (vf2{uA.z, uB.z} + sp(U_HOVER));
  vf2 su3 = sp(ACT_SCALE) * (vf2{uA.w, uB.w} + sp(U_HOVER));
  vf2 Fz  = ((su0 + su1) + su2) + su3;
  FzM  = Fz * sp(INV_MASS);
  tauz = sp(KM) * (((su0 - su1) + su2) - su3);
  taux = ((sp(TAUC) * su0 + sp(-TAUC) * su1) + sp(-TAUC) * su2) + sp(TAUC) * su3;
  tauy = ((sp(-TAUC) * su0 + sp(-TAUC) * su1) + sp(TAUC) * su2) + sp(TAUC) * su3;
}

// PURE-REGISTER kernel: no LDS, no barriers, no explicit waits. Thread owns
// adjacent rows 2p,2p+1 = 7 contiguous CACHED vf4 loads (112 B; L1 absorbs the
// cross-lane line overlap - R7's blowup was the nt hint bypassing L1, R5's was
// nt 8B stores) -> free register transpose -> packed RK4 -> 7 contiguous
// CACHED vf4 stores (R11-proven: WRITE stays ~116 MB, lines fully covered).
__global__ __launch_bounds__(256) void fc_rk4_kernel(const float* __restrict__ x,
                                                     const float* __restrict__ u,
                                                     float* __restrict__ out,
                                                     int n) {
  const long long pair = (long long)blockIdx.x * 256 + threadIdx.x;
  const long long row = 2 * pair;
  if (row + 1 < n) {
    // ---- 7 cached vf4 loads (row even -> 16B aligned) ----
    const vf4* g = (const vf4*)(x + row * 14);
    vf4 a0 = g[0], a1 = g[1], a2 = g[2], a3 = g[3], a4 = g[4], a5 = g[5], a6 = g[6];

    const vf4* ug = (const vf4*)(u + row * 4);
    vf4 uA = ug[0], uB = ug[1];
    vf2 FzM, taux, tauy, tauz;
    utau(uA, uB, FzM, taux, tauy, tauz);

    // rowA = words 0..13, rowB = words 14..27; x0[j] = {rowA[j], rowB[j]}
    vf2 x0[14] = {
      {a0.x, a3.z}, {a0.y, a3.w}, {a0.z, a4.x}, {a0.w, a4.y},
      {a1.x, a4.z}, {a1.y, a4.w}, {a1.z, a5.x}, {a1.w, a5.y},
      {a2.x, a5.z}, {a2.y, a5.w}, {a2.z, a6.x}, {a2.w, a6.y},
      {a3.x, a6.z}, {a3.y, a6.w}};

    vf2 o[14];
    rk4_core(x0, FzM, taux, tauy, tauz, o);

    // ---- 7 cached vf4 stores ----
    vf4* ob = (vf4*)(out + row * 14);
    ob[0] = vf4{o[0].x,  o[1].x,  o[2].x,  o[3].x};
    ob[1] = vf4{o[4].x,  o[5].x,  o[6].x,  o[7].x};
    ob[2] = vf4{o[8].x,  o[9].x,  o[10].x, o[11].x};
    ob[3] = vf4{o[12].x, o[13].x, o[0].y,  o[1].y};
    ob[4] = vf4{o[2].y,  o[3].y,  o[4].y,  o[5].y};
    ob[5] = vf4{o[6].y,  o[7].y,  o[8].y,  o[9].y};
    ob[6] = vf4{o[10].y, o[11].y, o[12].y, o[13].y};
  } else if (row < n) {
    // last odd row (not hit at B=2M): scalar path, row duplicated in both lanes
    vf2 x0[14];
    #pragma unroll
    for (int j = 0; j < 14; ++j) { float v = x[row * 14 + j]; x0[j] = vf2{v, v}; }
    vf4 uv = *(const vf4*)(u + row * 4);
    vf2 FzM, taux, tauy, tauz;
    utau(uv, uv, FzM, taux, tauy, tauz);
    vf2 o[14];
    rk4_core(x0, FzM, taux, tauy, tauz, o);
    #pragma unroll
    for (int j = 0; j < 14; ++j) out[row * 14 + j] = o[j].x;
  }
}

}  // namespace fc

extern "C" void kernel_launch(void* const* d_in, const int* in_sizes, int n_in,
                              void* d_out, int out_size, void* d_ws, size_t ws_size,
                              hipStream_t stream) {
  const float* x = (const float*)d_in[0];
  const float* u = (const float*)d_in[1];
  float* out = (float*)d_out;
  const int n = in_sizes[0] / 14;
  const long long pairs = ((long long)n + 1) / 2;
  const int grid = (int)((pairs + 255) / 256);
  hipLaunchKernelGGL(fc::fc_rk4_kernel, dim3(grid), dim3(256), 0, stream,
                     x, u, out, n);
}

// Round 15
// 46.287 us; speedup vs baseline: 1.1254x; 1.1254x over previous
//
#include <hip/hip_runtime.h>
#include <math.h>

namespace fc {

typedef float vf2 __attribute__((ext_vector_type(2)));
typedef float vf4 __attribute__((ext_vector_type(4)));

__device__ __forceinline__ vf2 sp(float c) { return vf2{c, c}; }

constexpr float ACT_SCALE = 10.0f;
constexpr float U_HOVER   = 0.515025f;          // -MASS*-9.81/10/1/4
constexpr float INV_MASS  = 1.0f / 2.1f;
constexpr float KM        = 0.025f;
constexpr float TAUC      = 0.175f * 0.70710678f; // MOTOR_DIST / sqrt(2)
constexpr float JXY       = 0.0023f;
constexpr float JZ        = 0.004f;
constexpr float INV_JXY   = 1.0f / 0.0023f;
constexpr float INV_JZ    = 1.0f / 0.004f;
constexpr float G3        = -9.81f;
constexpr float INV_L     = 2.0f;
constexpr float DT        = 0.05f;
constexpr float DT2       = 0.05f * 0.5f;
constexpr float DT6       = 0.05f / 6.0f;

// Packed (2 rows/lane) dynamics. FzM = Fz/MASS precomputed (stage-invariant).
__device__ __forceinline__ void dyn2(const vf2* xt, vf2 FzM,
                                     vf2 taux, vf2 tauy, vf2 tauz, vf2* dx) {
  vf2 mx = xt[3], my = xt[4], mz = xt[5], th = xt[6];
  vf2 vx = xt[7], vy = xt[8], vz = xt[9];
  vf2 wx = xt[10], wy = xt[11], wz = xt[12];

  vf2 n2 = mx * mx + my * my + mz * mz;
  vf2 inv;
  inv.x = __builtin_amdgcn_rcpf(1.0f + n2.x);
  inv.y = __builtin_amdgcn_rcpf(1.0f + n2.y);
  vf2 s  = (sp(1.0f) - n2) * inv;
  vf2 qx = sp(2.0f) * mx * inv;
  vf2 qy = sp(2.0f) * my * inv;
  vf2 qz = sp(2.0f) * mz * inv;

  // gravity rotation quatrot(-q, (0,0,g)) hand-specialized (exact: dropped
  // terms are *0.0); g applied directly (MASS*g/MASS folded).
  vf2 gtx = qy * sp(-G3);
  vf2 gty = qx * sp(G3);
  vf2 gtz = s * sp(G3);
  vf2 gx = sp(-2.0f) * (qy * gtz - qz * gty);
  vf2 gy = sp(-2.0f) * (qz * gtx - qx * gtz);
  vf2 gz = sp(G3) + sp(-2.0f) * (qx * gty - qy * gtx);

  // pdot = quatrot(q, v)
  vf2 tx = qy * vz - qz * vy + s * vx;
  vf2 ty = qz * vx - qx * vz + s * vy;
  vf2 tz = qx * vy - qy * vx + s * vz;
  dx[0] = vx + sp(2.0f) * (qy * tz - qz * ty);
  dx[1] = vy + sp(2.0f) * (qz * tx - qx * tz);
  dx[2] = vz + sp(2.0f) * (qx * ty - qy * tx);

  // mdot
  vf2 mw  = mx * wx + my * wy + mz * wz;
  vf2 on2 = sp(1.0f) - n2;
  dx[3] = sp(0.25f) * (on2 * wx + sp(2.0f) * (my * wz - mz * wy) + sp(2.0f) * mx * mw);
  dx[4] = sp(0.25f) * (on2 * wy + sp(2.0f) * (mz * wx - mx * wz) + sp(2.0f) * my * mw);
  dx[5] = sp(0.25f) * (on2 * wz + sp(2.0f) * (mx * wy - my * wx) + sp(2.0f) * mz * mw);

  dx[6] = xt[13];

  // vdot = (0,0,Fz/M) + g' - w x v
  vf2 vdx = gx - (wy * vz - wz * vy);
  vf2 vdy = gy - (wz * vx - wx * vz);
  vf2 vdz = FzM + gz - (wx * vy - wy * vx);
  dx[7] = vdx; dx[8] = vdy; dx[9] = vdz;

  // wdot
  vf2 Jwx = sp(JXY) * wx, Jwy = sp(JXY) * wy, Jwz = sp(JZ) * wz;
  dx[10] = (taux - (wy * Jwz - wz * Jwy)) * sp(INV_JXY);
  dx[11] = (tauy - (wz * Jwx - wx * Jwz)) * sp(INV_JXY);
  dx[12] = (tauz - (wx * Jwy - wy * Jwx)) * sp(INV_JZ);

  // x_ddot = quatrot(q, vdot).x only
  vf2 t2y = qz * vdx - qx * vdz + s * vdy;
  vf2 t2z = qx * vdy - qy * vdx + s * vdz;
  vf2 rx  = vdx + sp(2.0f) * (qy * t2z - qz * t2y);
  vf2 st, ct;
  st.x = __sinf(th.x); st.y = __sinf(th.y);
  ct.x = __cosf(th.x); ct.y = __cosf(th.y);
  dx[13] = (sp(G3) * st + rx * ct) * sp(INV_L);
}

__device__ __forceinline__ void rk4_core(const vf2* x0, vf2 FzM,
                                         vf2 taux, vf2 tauy, vf2 tauz, vf2* o) {
  vf2 xt[14], kk[14], acc[14];
  dyn2(x0, FzM, taux, tauy, tauz, kk);
  #pragma unroll
  for (int j = 0; j < 14; ++j) { acc[j] = kk[j]; xt[j] = x0[j] + sp(DT2) * kk[j]; }
  dyn2(xt, FzM, taux, tauy, tauz, kk);
  #pragma unroll
  for (int j = 0; j < 14; ++j) { acc[j] += sp(2.0f) * kk[j]; xt[j] = x0[j] + sp(DT2) * kk[j]; }
  dyn2(xt, FzM, taux, tauy, tauz, kk);
  #pragma unroll
  for (int j = 0; j < 14; ++j) { acc[j] += sp(2.0f) * kk[j]; xt[j] = x0[j] + sp(DT) * kk[j]; }
  dyn2(xt, FzM, taux, tauy, tauz, kk);
  #pragma unroll
  for (int j = 0; j < 14; ++j) o[j] = x0[j] + sp(DT6) * (acc[j] + kk[j]);
}

__device__ __forceinline__ void utau(vf4 uA, vf4 uB, vf2& FzM,
                                     vf2& taux, vf2& tauy, vf2& tauz) {
  vf2 su0 = sp(ACT_SCALE) * (vf2{uA.x, uB.x} + sp(U_HOVER));
  vf2 su1 = sp(ACT_SCALE) * (vf2{uA.y, uB.y} + sp(U_HOVER));
  vf2 su2 = sp(ACT_SCALE) * (vf2{uA.z, uB.z} + sp(U_HOVER));
  vf2 su3 = sp(ACT_SCALE) * (vf2{uA.w, uB.w} + sp(U_HOVER));
  vf2 Fz  = ((su0 + su1) + su2) + su3;
  FzM  = Fz * sp(INV_MASS);
  tauz = sp(KM) * (((su0 - su1) + su2) - su3);
  taux = ((sp(TAUC) * su0 + sp(-TAUC) * su1) + sp(-TAUC) * su2) + sp(TAUC) * su3;
  tauy = ((sp(-TAUC) * su0 + sp(-TAUC) * su1) + sp(TAUC) * su2) + sp(TAUC) * su3;
}

// Split-phase double-tile per wave (MLP fix): stage T0 AND T1 up front
// (18 KB in flight/wave), vmcnt(9) releases T0+u0 while T1 flies under T0's
// compute; vmcnt(7) then releases T1+u1 and leaves T0's stores in flight
// (never drains to 0). Zero barriers - waves fully autonomous (R13 base).
__global__ __launch_bounds__(128) void fc_rk4_kernel(const float* __restrict__ x,
                                                     const float* __restrict__ u,
                                                     float* __restrict__ out,
                                                     int n) {
  __shared__ float xs[2 * 2 * 1792];  // 2 waves x 2 tiles x 7168 B = 28672 B
  const int t = threadIdx.x;
  const int lane = t & 63;
  const int w = t >> 6;
  const long long base = (long long)blockIdx.x * 512;

  if (base + 512 <= (long long)n) {
    const long long r0 = base + w * 256;        // wave's T0 rows
    const long long r1 = r0 + 128;              // wave's T1 rows
    float* ws0 = xs + w * 3584;
    float* ws1 = ws0 + 1792;

    typedef const __attribute__((address_space(1))) float gbl_f;
    auto stage = [&](long long row, float* dst) {
      gbl_f* gsrc = (gbl_f*)(x + row * 14);
      #pragma unroll
      for (int k = 0; k < 7; ++k)
        __builtin_amdgcn_global_load_lds(
            (const __attribute__((address_space(1))) void*)(gsrc + k * 256 + lane * 4),
            (__attribute__((address_space(3))) void*)((__attribute__((address_space(3))) float*)dst + k * 256),
            16, 0, 0);
    };

    // ---- issue everything: T0(7), u0(2), T1(7), u1(2) = 18 outstanding ----
    stage(r0, ws0);
    const vf4* ug0 = (const vf4*)(u + r0 * 4);
    vf4 uA0 = ug0[2 * lane], uB0 = ug0[2 * lane + 1];
    stage(r1, ws1);
    const vf4* ug1 = (const vf4*)(u + r1 * 4);
    vf4 uA1 = ug1[2 * lane], uB1 = ug1[2 * lane + 1];

    vf2 FzM0, tx0, ty0, tz0;
    utau(uA0, uB0, FzM0, tx0, ty0, tz0);  // waits only on u0 (compiler vmcnt)

    // T0 + u0 retired; T1 + u1 (9 youngest) stay in flight
    asm volatile("s_waitcnt vmcnt(9)" ::: "memory");

    // ---- tile 0: gather, compute, write-back, drain ----
    vf4* mine0 = (vf4*)(ws0 + lane * 28);
    vf4 a0 = mine0[0], a1 = mine0[1], a2 = mine0[2], a3 = mine0[3],
        a4 = mine0[4], a5 = mine0[5], a6 = mine0[6];
    vf2 x0[14] = {
      {a0.x, a3.z}, {a0.y, a3.w}, {a0.z, a4.x}, {a0.w, a4.y},
      {a1.x, a4.z}, {a1.y, a4.w}, {a1.z, a5.x}, {a1.w, a5.y},
      {a2.x, a5.z}, {a2.y, a5.w}, {a2.z, a6.x}, {a2.w, a6.y},
      {a3.x, a6.z}, {a3.y, a6.w}};

    vf2 o[14];
    rk4_core(x0, FzM0, tx0, ty0, tz0, o);   // T1's HBM latency hides here

    mine0[0] = vf4{o[0].x,  o[1].x,  o[2].x,  o[3].x};
    mine0[1] = vf4{o[4].x,  o[5].x,  o[6].x,  o[7].x};
    mine0[2] = vf4{o[8].x,  o[9].x,  o[10].x, o[11].x};
    mine0[3] = vf4{o[12].x, o[13].x, o[0].y,  o[1].y};
    mine0[4] = vf4{o[2].y,  o[3].y,  o[4].y,  o[5].y};
    mine0[5] = vf4{o[6].y,  o[7].y,  o[8].y,  o[9].y};
    mine0[6] = vf4{o[10].y, o[11].y, o[12].y, o[13].y};
    asm volatile("s_waitcnt lgkmcnt(0)" ::: "memory");

    const vf4* ws04 = (const vf4*)ws0;
    vf4* og0 = (vf4*)(out + r0 * 14);
    #pragma unroll
    for (int k = 0; k < 7; ++k)
      __builtin_nontemporal_store(ws04[k * 64 + lane], og0 + k * 64 + lane);

    vf2 FzM1, tx1, ty1, tz1;
    utau(uA1, uB1, FzM1, tx1, ty1, tz1);

    // outstanding = T1(7)+u1(2)+stores0(7)=16; retire 9 oldest = T1+u1,
    // keep stores0 in flight (T4: never drain to 0 mid-kernel).
    asm volatile("s_waitcnt vmcnt(7)" ::: "memory");

    // ---- tile 1: gather, compute, write-back, drain ----
    vf4* mine1 = (vf4*)(ws1 + lane * 28);
    vf4 b0 = mine1[0], b1 = mine1[1], b2 = mine1[2], b3 = mine1[3],
        b4 = mine1[4], b5 = mine1[5], b6 = mine1[6];
    vf2 x1[14] = {
      {b0.x, b3.z}, {b0.y, b3.w}, {b0.z, b4.x}, {b0.w, b4.y},
      {b1.x, b4.z}, {b1.y, b4.w}, {b1.z, b5.x}, {b1.w, b5.y},
      {b2.x, b5.z}, {b2.y, b5.w}, {b2.z, b6.x}, {b2.w, b6.y},
      {b3.x, b6.z}, {b3.y, b6.w}};

    vf2 o1[14];
    rk4_core(x1, FzM1, tx1, ty1, tz1, o1);

    mine1[0] = vf4{o1[0].x,  o1[1].x,  o1[2].x,  o1[3].x};
    mine1[1] = vf4{o1[4].x,  o1[5].x,  o1[6].x,  o1[7].x};
    mine1[2] = vf4{o1[8].x,  o1[9].x,  o1[10].x, o1[11].x};
    mine1[3] = vf4{o1[12].x, o1[13].x, o1[0].y,  o1[1].y};
    mine1[4] = vf4{o1[2].y,  o1[3].y,  o1[4].y,  o1[5].y};
    mine1[5] = vf4{o1[6].y,  o1[7].y,  o1[8].y,  o1[9].y};
    mine1[6] = vf4{o1[10].y, o1[11].y, o1[12].y, o1[13].y};
    asm volatile("s_waitcnt lgkmcnt(0)" ::: "memory");

    const vf4* ws14 = (const vf4*)ws1;
    vf4* og1 = (vf4*)(out + r1 * 14);
    #pragma unroll
    for (int k = 0; k < 7; ++k)
      __builtin_nontemporal_store(ws14[k * 64 + lane], og1 + k * 64 + lane);
  } else {
    // tail (not hit at B=2M): per-row scalar path, 4 rows/thread
    #pragma unroll
    for (int k = 0; k < 4; ++k) {
      long long r = base + t + 128LL * k;
      if (r < n) {
        vf2 x0[14];
        #pragma unroll
        for (int j = 0; j < 14; ++j) { float v = x[r * 14 + j]; x0[j] = vf2{v, v}; }
        vf4 uv = *(const vf4*)(u + r * 4);
        vf2 FzM, taux, tauy, tauz;
        utau(uv, uv, FzM, taux, tauy, tauz);
        vf2 o[14];
        rk4_core(x0, FzM, taux, tauy, tauz, o);
        #pragma unroll
        for (int j = 0; j < 14; ++j) out[r * 14 + j] = o[j].x;
      }
    }
  }
}

}  // namespace fc

extern "C" void kernel_launch(void* const* d_in, const int* in_sizes, int n_in,
                              void* d_out, int out_size, void* d_ws, size_t ws_size,
                              hipStream_t stream) {
  const float* x = (const float*)d_in[0];
  const float* u = (const float*)d_in[1];
  float* out = (float*)d_out;
  const int n = in_sizes[0] / 14;
  const int grid = (n + 511) / 512;
  hipLaunchKernelGGL(fc::fc_rk4_kernel, dim3(grid), dim3(128), 0, stream,
                     x, u, out, n);
}

// Round 16
// 46.165 us; speedup vs baseline: 1.1284x; 1.0026x over previous
//
#include <hip/hip_runtime.h>
#include <math.h>

namespace fc {

typedef float vf2 __attribute__((ext_vector_type(2)));
typedef float vf4 __attribute__((ext_vector_type(4)));

__device__ __forceinline__ vf2 sp(float c) { return vf2{c, c}; }

constexpr float ACT_SCALE = 10.0f;
constexpr float U_HOVER   = 0.515025f;          // -MASS*-9.81/10/1/4
constexpr float INV_MASS  = 1.0f / 2.1f;
constexpr float KM        = 0.025f;
constexpr float TAUC      = 0.175f * 0.70710678f; // MOTOR_DIST / sqrt(2)
constexpr float JXY       = 0.0023f;
constexpr float JZ        = 0.004f;
constexpr float INV_JXY   = 1.0f / 0.0023f;
constexpr float INV_JZ    = 1.0f / 0.004f;
constexpr float G3        = -9.81f;
constexpr float INV_L     = 2.0f;
constexpr float DT        = 0.05f;
constexpr float DT2       = 0.05f * 0.5f;
constexpr float DT6       = 0.05f / 6.0f;

// Packed (2 rows/lane) dynamics. FzM = Fz/MASS precomputed (stage-invariant).
__device__ __forceinline__ void dyn2(const vf2* xt, vf2 FzM,
                                     vf2 taux, vf2 tauy, vf2 tauz, vf2* dx) {
  vf2 mx = xt[3], my = xt[4], mz = xt[5], th = xt[6];
  vf2 vx = xt[7], vy = xt[8], vz = xt[9];
  vf2 wx = xt[10], wy = xt[11], wz = xt[12];

  vf2 n2 = mx * mx + my * my + mz * mz;
  vf2 inv;
  inv.x = __builtin_amdgcn_rcpf(1.0f + n2.x);
  inv.y = __builtin_amdgcn_rcpf(1.0f + n2.y);
  vf2 s  = (sp(1.0f) - n2) * inv;
  vf2 qx = sp(2.0f) * mx * inv;
  vf2 qy = sp(2.0f) * my * inv;
  vf2 qz = sp(2.0f) * mz * inv;

  // gravity rotation quatrot(-q, (0,0,g)) hand-specialized (exact: dropped
  // terms are *0.0); g applied directly (MASS*g/MASS folded).
  vf2 gtx = qy * sp(-G3);
  vf2 gty = qx * sp(G3);
  vf2 gtz = s * sp(G3);
  vf2 gx = sp(-2.0f) * (qy * gtz - qz * gty);
  vf2 gy = sp(-2.0f) * (qz * gtx - qx * gtz);
  vf2 gz = sp(G3) + sp(-2.0f) * (qx * gty - qy * gtx);

  // pdot = quatrot(q, v)
  vf2 tx = qy * vz - qz * vy + s * vx;
  vf2 ty = qz * vx - qx * vz + s * vy;
  vf2 tz = qx * vy - qy * vx + s * vz;
  dx[0] = vx + sp(2.0f) * (qy * tz - qz * ty);
  dx[1] = vy + sp(2.0f) * (qz * tx - qx * tz);
  dx[2] = vz + sp(2.0f) * (qx * ty - qy * tx);

  // mdot
  vf2 mw  = mx * wx + my * wy + mz * wz;
  vf2 on2 = sp(1.0f) - n2;
  dx[3] = sp(0.25f) * (on2 * wx + sp(2.0f) * (my * wz - mz * wy) + sp(2.0f) * mx * mw);
  dx[4] = sp(0.25f) * (on2 * wy + sp(2.0f) * (mz * wx - mx * wz) + sp(2.0f) * my * mw);
  dx[5] = sp(0.25f) * (on2 * wz + sp(2.0f) * (mx * wy - my * wx) + sp(2.0f) * mz * mw);

  dx[6] = xt[13];

  // vdot = (0,0,Fz/M) + g' - w x v
  vf2 vdx = gx - (wy * vz - wz * vy);
  vf2 vdy = gy - (wz * vx - wx * vz);
  vf2 vdz = FzM + gz - (wx * vy - wy * vx);
  dx[7] = vdx; dx[8] = vdy; dx[9] = vdz;

  // wdot
  vf2 Jwx = sp(JXY) * wx, Jwy = sp(JXY) * wy, Jwz = sp(JZ) * wz;
  dx[10] = (taux - (wy * Jwz - wz * Jwy)) * sp(INV_JXY);
  dx[11] = (tauy - (wz * Jwx - wx * Jwz)) * sp(INV_JXY);
  dx[12] = (tauz - (wx * Jwy - wy * Jwx)) * sp(INV_JZ);

  // x_ddot = quatrot(q, vdot).x only
  vf2 t2y = qz * vdx - qx * vdz + s * vdy;
  vf2 t2z = qx * vdy - qy * vdx + s * vdz;
  vf2 rx  = vdx + sp(2.0f) * (qy * t2z - qz * t2y);
  vf2 st, ct;
  st.x = __sinf(th.x); st.y = __sinf(th.y);
  ct.x = __cosf(th.x); ct.y = __cosf(th.y);
  dx[13] = (sp(G3) * st + rx * ct) * sp(INV_L);
}

__device__ __forceinline__ void rk4_core(const vf2* x0, vf2 FzM,
                                         vf2 taux, vf2 tauy, vf2 tauz, vf2* o) {
  vf2 xt[14], kk[14], acc[14];
  dyn2(x0, FzM, taux, tauy, tauz, kk);
  #pragma unroll
  for (int j = 0; j < 14; ++j) { acc[j] = kk[j]; xt[j] = x0[j] + sp(DT2) * kk[j]; }
  dyn2(xt, FzM, taux, tauy, tauz, kk);
  #pragma unroll
  for (int j = 0; j < 14; ++j) { acc[j] += sp(2.0f) * kk[j]; xt[j] = x0[j] + sp(DT2) * kk[j]; }
  dyn2(xt, FzM, taux, tauy, tauz, kk);
  #pragma unroll
  for (int j = 0; j < 14; ++j) { acc[j] += sp(2.0f) * kk[j]; xt[j] = x0[j] + sp(DT) * kk[j]; }
  dyn2(xt, FzM, taux, tauy, tauz, kk);
  #pragma unroll
  for (int j = 0; j < 14; ++j) o[j] = x0[j] + sp(DT6) * (acc[j] + kk[j]);
}

__device__ __forceinline__ void utau(vf4 uA, vf4 uB, vf2& FzM,
                                     vf2& taux, vf2& tauy, vf2& tauz) {
  vf2 su0 = sp(ACT_SCALE) * (vf2{uA.x, uB.x} + sp(U_HOVER));
  vf2 su1 = sp(ACT_SCALE) * (vf2{uA.y, uB.y} + sp(U_HOVER));
  vf2 su2 = sp(ACT_SCALE) * (vf2{uA.z, uB.z} + sp(U_HOVER));
  vf2 su3 = sp(ACT_SCALE) * (vf2{uA.w, uB.w} + sp(U_HOVER));
  vf2 Fz  = ((su0 + su1) + su2) + su3;
  FzM  = Fz * sp(INV_MASS);
  tauz = sp(KM) * (((su0 - su1) + su2) - su3);
  taux = ((sp(TAUC) * su0 + sp(-TAUC) * su1) + sp(-TAUC) * su2) + sp(TAUC) * su3;
  tauy = ((sp(-TAUC) * su0 + sp(-TAUC) * su1) + sp(TAUC) * su2) + sp(TAUC) * su3;
}

// R13 winner, single variable changed: drain stores are PLAIN CACHED (no
// nontemporal hint). nt bypasses L2/L3 write-combining; the harness fill
// kernel sustains 7 TB/s with cached stores vs our 2.5 TB/s write rate.
__global__ __launch_bounds__(128) void fc_rk4_kernel(const float* __restrict__ x,
                                                     const float* __restrict__ u,
                                                     float* __restrict__ out,
                                                     int n) {
  __shared__ float xs[2 * 1792];  // 14336 B, one 7168 B region per wave
  const int t = threadIdx.x;
  const int lane = t & 63;
  const int w = t >> 6;
  const long long base = (long long)blockIdx.x * 256;

  if (base + 256 <= (long long)n) {
    const long long wrow = base + w * 128;      // this wave's 128 rows
    float* ws = xs + w * 1792;

    // ---- direct global->LDS staging: 7x global_load_lds_dwordx4 ----
    typedef const __attribute__((address_space(1))) float gbl_f;
    gbl_f* gsrc = (gbl_f*)(x + wrow * 14);
    #pragma unroll
    for (int k = 0; k < 7; ++k)
      __builtin_amdgcn_global_load_lds(
          (const __attribute__((address_space(1))) void*)(gsrc + k * 256 + lane * 4),
          (__attribute__((address_space(3))) void*)((__attribute__((address_space(3))) float*)ws + k * 256),
          16, 0, 0);

    // u rows + stage-invariant thrust/torque math: overlaps staging latency
    const vf4* ug = (const vf4*)(u + wrow * 4);
    vf4 uA = ug[2 * lane], uB = ug[2 * lane + 1];
    vf2 FzM, taux, tauy, tauz;
    utau(uA, uB, FzM, taux, tauy, tauz);

    asm volatile("s_waitcnt vmcnt(0)" ::: "memory");  // wave-local stall only

    // ---- own-rows gather: 7x ds_read_b128, word-stride 28 (conflict-free) ----
    vf4* mine = (vf4*)(ws + lane * 28);
    vf4 a0 = mine[0], a1 = mine[1], a2 = mine[2], a3 = mine[3],
        a4 = mine[4], a5 = mine[5], a6 = mine[6];
    vf2 x0[14] = {
      {a0.x, a3.z}, {a0.y, a3.w}, {a0.z, a4.x}, {a0.w, a4.y},
      {a1.x, a4.z}, {a1.y, a4.w}, {a1.z, a5.x}, {a1.w, a5.y},
      {a2.x, a5.z}, {a2.y, a5.w}, {a2.z, a6.x}, {a2.w, a6.y},
      {a3.x, a6.z}, {a3.y, a6.w}};

    vf2 o[14];
    rk4_core(x0, FzM, taux, tauy, tauz, o);

    // ---- write back own rows: 7x ds_write_b128 ----
    mine[0] = vf4{o[0].x,  o[1].x,  o[2].x,  o[3].x};
    mine[1] = vf4{o[4].x,  o[5].x,  o[6].x,  o[7].x};
    mine[2] = vf4{o[8].x,  o[9].x,  o[10].x, o[11].x};
    mine[3] = vf4{o[12].x, o[13].x, o[0].y,  o[1].y};
    mine[4] = vf4{o[2].y,  o[3].y,  o[4].y,  o[5].y};
    mine[5] = vf4{o[6].y,  o[7].y,  o[8].y,  o[9].y};
    mine[6] = vf4{o[10].y, o[11].y, o[12].y, o[13].y};
    asm volatile("s_waitcnt lgkmcnt(0)" ::: "memory");  // wave-local

    // ---- coalesced CACHED drain of wave region (the A/B variable) ----
    const vf4* ws4 = (const vf4*)ws;
    vf4* og4 = (vf4*)(out + wrow * 14);
    #pragma unroll
    for (int k = 0; k < 7; ++k)
      og4[k * 64 + lane] = ws4[k * 64 + lane];
  } else {
    // tail (not hit at B=2M): per-row scalar path, row duplicated in both lanes
    #pragma unroll
    for (int k = 0; k < 2; ++k) {
      long long r = base + 2LL * t + k;
      if (r < n) {
        vf2 x0[14];
        #pragma unroll
        for (int j = 0; j < 14; ++j) { float v = x[r * 14 + j]; x0[j] = vf2{v, v}; }
        vf4 uv = *(const vf4*)(u + r * 4);
        vf2 FzM, taux, tauy, tauz;
        utau(uv, uv, FzM, taux, tauy, tauz);
        vf2 o[14];
        rk4_core(x0, FzM, taux, tauy, tauz, o);
        #pragma unroll
        for (int j = 0; j < 14; ++j) out[r * 14 + j] = o[j].x;
      }
    }
  }
}

}  // namespace fc

extern "C" void kernel_launch(void* const* d_in, const int* in_sizes, int n_in,
                              void* d_out, int out_size, void* d_ws, size_t ws_size,
                              hipStream_t stream) {
  const float* x = (const float*)d_in[0];
  const float* u = (const float*)d_in[1];
  float* out = (float*)d_out;
  const int n = in_sizes[0] / 14;
  const int grid = (n + 255) / 256;
  hipLaunchKernelGGL(fc::fc_rk4_kernel, dim3(grid), dim3(128), 0, stream,
                     x, u, out, n);
}